// Round 19
// baseline (292.615 us; speedup 1.0000x reference)
//
#include <hip/hip_runtime.h>
#include <cmath>

#define B_SZ    4
#define N_SEQ   1536
#define D_MODEL 1536
#define H_N     8
#define DK      64
#define DV      192
#define HDK     512
#define HDV     1536
#define NRPF    192
#define NB      32
#define NREL    3071
#define QKS     2560   // row stride of fused q|k|v buffer
#define SM_BASE 12.0f  // fixed softmax base: p = exp(S - SM_BASE); |S| <= ~30 (verified r8)

typedef unsigned short u16;
typedef __attribute__((ext_vector_type(8))) short short8;
typedef __attribute__((ext_vector_type(4))) float f32x4;

#define MFMA_B16(a, b, c) __builtin_amdgcn_mfma_f32_16x16x32_bf16(a, b, c, 0, 0, 0)

__device__ __forceinline__ float bf2f(u16 u) {
    union { unsigned u; float f; } x; x.u = ((unsigned)u) << 16; return x.f;
}
__device__ __forceinline__ u16 f2bf(float f) {
    union { float f; unsigned u; } x; x.f = f;
    unsigned r = x.u + 0x7FFFu + ((x.u >> 16) & 1u);
    return (u16)(r >> 16);
}
__device__ __forceinline__ void gload16(const u16* g, u16* l) {
    __builtin_amdgcn_global_load_lds(
        (const __attribute__((address_space(1))) unsigned int*)(const void*)g,
        (__attribute__((address_space(3))) unsigned int*)(void*)l, 16, 0, 0);
}

// ---------------- fused prep: weight transposes (z=0..4), pos embed (z=5), cvt (z=6) --
// grid dim3(64, 48, 7), 256 threads.
__global__ __launch_bounds__(256) void prep_kernel(
    const float* __restrict__ x,
    const float* __restrict__ Wq, const float* __restrict__ Wk,
    const float* __restrict__ Wv, const float* __restrict__ Wout,
    const float* __restrict__ Wrel,
    u16* __restrict__ posb, u16* __restrict__ xb,
    u16* __restrict__ wqkvt, u16* __restrict__ woutt, u16* __restrict__ wrelt) {
    const int z = blockIdx.z;
    const int tid = threadIdx.x;
    if (z < 5) {
        // ---- weight transpose: W (KxN f32) -> Wt (NxK bf16), scaled ----
        const float* W; u16* Wt; int K, N; float scale = 1.0f;
        if (z == 0)      { W = Wq;   Wt = wqkvt;                        K = 1536; N = 512;  scale = 0.125f; }
        else if (z == 1) { W = Wk;   Wt = wqkvt + (size_t)512 * 1536;   K = 1536; N = 512;  }
        else if (z == 2) { W = Wv;   Wt = wqkvt + (size_t)1024 * 1536;  K = 1536; N = 1536; }
        else if (z == 3) { W = Wout; Wt = woutt;                        K = 1536; N = 1536; }
        else             { W = Wrel; Wt = wrelt;                        K = 192;  N = 512;  }
        __shared__ float tile[32][33];
        int n0 = blockIdx.x * 32, k0 = blockIdx.y * 32;
        if (n0 >= N || k0 >= K) return;
        int tx = tid & 31, ty = tid >> 5;
        for (int r = ty; r < 32; r += 8) tile[r][tx] = W[(size_t)(k0 + r) * N + n0 + tx];
        __syncthreads();
        for (int r = ty; r < 32; r += 8)
            Wt[(size_t)(n0 + r) * K + k0 + tx] = f2bf(tile[tx][r] * scale);
    } else if (z == 5) {
        // ---- positional embedding -> bf16 (3072 x 192, row 3071 = 0) ----
        const int r = blockIdx.y * 64 + blockIdx.x;   // 0..3071
        const int j = tid;                            // only 0..95 active
        if (r >= NREL) {
            if (j < 96) {
                posb[(size_t)r * NRPF + j] = 0;
                posb[(size_t)r * NRPF + 96 + j] = 0;
            }
            return;
        }
        __shared__ float gprobs[NB];
        float dist = (float)(r - (N_SEQ - 1));
        float absd = fabsf(dist);
        int cls = j >> 5, jj = j & 31;
        float val = 0.0f;
        if (j < 96) {
            if (cls == 0) {
                const float max_range = 10.584962500721156f; // log2(1536)
                float hl = exp2f(3.0f + (float)jj * (max_range - 3.0f) / 31.0f);
                val = expf(-0.6931471805599453f / hl * absd);
            } else if (cls == 1) {
                float cw = exp2f((float)(jj + 1)) - 1.0f;
                val = (cw > absd) ? 1.0f : 0.0f;
            } else {
                float mean = 48.0f + (float)jj * (1536.0f - 48.0f) / 31.0f;
                float conc = (mean / 24.0f) * (mean / 24.0f);
                float rate = mean / 576.0f;
                float lu = (conc - 1.0f) * logf(absd) - rate * absd;
                float ln = lgammaf(conc) - conc * logf(rate);
                float prob = expf(lu - ln) + 1e-8f;
                gprobs[jj] = prob;
                val = prob;
            }
        }
        __syncthreads();
        if (j < 96) {
            if (cls == 2) {
                float mx = gprobs[0];
                #pragma unroll
                for (int t = 1; t < NB; ++t) mx = fmaxf(mx, gprobs[t]);
                val = val / mx;
            }
            float sgn = (dist > 0.f) ? 1.f : ((dist < 0.f) ? -1.f : 0.f);
            posb[(size_t)r * NRPF + j]      = f2bf(val);
            posb[(size_t)r * NRPF + 96 + j] = f2bf(sgn * val);
        }
    } else {
        // ---- x f32 -> bf16, grid-stride (n8 = 6144*1536/8) ----
        const int n8 = (B_SZ * N_SEQ) * D_MODEL / 8;
        const float4* p = (const float4*)x;
        for (int i = (blockIdx.y * 64 + blockIdx.x) * 256 + tid; i < n8; i += 64 * 48 * 256) {
            float4 a = p[i * 2], bq = p[i * 2 + 1];
            short8 o;
            o[0] = (short)f2bf(a.x);  o[1] = (short)f2bf(a.y);
            o[2] = (short)f2bf(a.z);  o[3] = (short)f2bf(a.w);
            o[4] = (short)f2bf(bq.x); o[5] = (short)f2bf(bq.y);
            o[6] = (short)f2bf(bq.z); o[7] = (short)f2bf(bq.w);
            *(short8*)(xb + (size_t)i * 8) = o;
        }
    }
}

// ---------------- bf16 MFMA GEMM body: C = A @ Bt^T (+bias) -----------------
#define BM 128
#define BN 128
#define BK 64
__device__ __forceinline__ void gemm_body(
    const u16* __restrict__ A, const u16* __restrict__ Bt,
    u16* __restrict__ Cb, float* __restrict__ Cf,
    const float* __restrict__ bias, int Mstore, int N, int K,
    int row0, int col0) {
    __shared__ u16 sA[BM * BK] __attribute__((aligned(16)));
    __shared__ u16 sB[BN * BK] __attribute__((aligned(16)));
    const int tid  = threadIdx.x;
    const int lane = tid & 63;
    const int w    = tid >> 6;
    const int wm   = w >> 1, wn = w & 1;

    f32x4 acc[4][4];
    #pragma unroll
    for (int i = 0; i < 4; ++i)
        #pragma unroll
        for (int j = 0; j < 4; ++j) acc[i][j] = (f32x4){0.f, 0.f, 0.f, 0.f};

    int srow[4], soff[4];
    #pragma unroll
    for (int i = 0; i < 4; ++i) {
        const int ci = i * 256 + tid;
        const int r  = ci >> 3;
        const int lc = (ci & 7) ^ (r & 7);
        srow[i] = r;
        soff[i] = lc * 8;
    }

    for (int kt = 0; kt < K; kt += BK) {
        #pragma unroll
        for (int i = 0; i < 4; ++i) {
            gload16(A + (size_t)(row0 + srow[i]) * K + kt + soff[i],
                    sA + (i * 256 + w * 64) * 8);
            gload16(Bt + (size_t)(col0 + srow[i]) * K + kt + soff[i],
                    sB + (i * 256 + w * 64) * 8);
        }
        __syncthreads();
        short8 af[2][4], bg[2][4];
        #pragma unroll
        for (int s = 0; s < 2; ++s) {
            #pragma unroll
            for (int mi = 0; mi < 4; ++mi) {
                const int rr = wm * 64 + mi * 16 + (lane & 15);
                af[s][mi] = *(const short8*)&sA[rr * 64 + (((s * 4 + (lane >> 4)) ^ (rr & 7)) * 8)];
            }
            #pragma unroll
            for (int ni = 0; ni < 4; ++ni) {
                const int rr = wn * 64 + ni * 16 + (lane & 15);
                bg[s][ni] = *(const short8*)&sB[rr * 64 + (((s * 4 + (lane >> 4)) ^ (rr & 7)) * 8)];
            }
        }
        #pragma unroll
        for (int s = 0; s < 2; ++s)
            #pragma unroll
            for (int mi = 0; mi < 4; ++mi)
                #pragma unroll
                for (int ni = 0; ni < 4; ++ni)
                    acc[mi][ni] = MFMA_B16(af[s][mi], bg[s][ni], acc[mi][ni]);
        __syncthreads();
    }
    const int rb = (lane >> 4) * 4;
    const int cl = lane & 15;
    #pragma unroll
    for (int mi = 0; mi < 4; ++mi) {
        #pragma unroll
        for (int r = 0; r < 4; ++r) {
            const int gr = row0 + wm * 64 + mi * 16 + rb + r;
            if (gr >= Mstore) continue;
            #pragma unroll
            for (int ni = 0; ni < 4; ++ni) {
                const int gc = col0 + wn * 64 + ni * 16 + cl;
                float v = acc[mi][ni][r];
                if (bias) v += bias[gc];
                if (Cb) Cb[(size_t)gr * N + gc] = f2bf(v);
                else    Cf[(size_t)gr * N + gc] = v;
            }
        }
    }
}

// T1 XCD swizzle: pin each A-row-panel's full column sweep to one XCD.
// Requires gy % 8 == 0 (bijective; ERRATA #11). flat follows dispatch order.
__device__ __forceinline__ void xcd_swz(int gx, int gy, int& bx, int& by) {
    const int flat = blockIdx.x + gx * blockIdx.y;
    const int ypg  = gy >> 3;             // y-panels per XCD
    const int xcd  = flat & 7;
    const int q    = flat >> 3;
    by = xcd * ypg + (q % ypg);
    bx = q / ypg;
}

__global__ __launch_bounds__(256) void gemm_bf16(
    const u16* __restrict__ A, const u16* __restrict__ Bt,
    u16* __restrict__ Cb, float* __restrict__ Cf,
    const float* __restrict__ bias, int Mstore, int N, int K) {
    int bx, by;
    xcd_swz(gridDim.x, gridDim.y, bx, by);
    gemm_body(A, Bt, Cb, Cf, bias, Mstore, N, K, by * BM, bx * BN);
}

// ---- fused QKV + rel GEMMs: z=0 QKV (6144x2560x1536, XCD-swizzled),
// ---- z=1 rel (3072x512x192, plain mapping + guard) ----
__global__ __launch_bounds__(256) void gemm_qkv_rel(
    const u16* __restrict__ xb, const u16* __restrict__ wqkvt, u16* __restrict__ qkvb,
    const u16* __restrict__ posb, const u16* __restrict__ wrelt, u16* __restrict__ relkb) {
    if (blockIdx.z == 0) {
        int bx, by;
        xcd_swz(QKS / BN, (B_SZ * N_SEQ) / BM, bx, by);   // 20 x 48
        gemm_body(xb, wqkvt, qkvb, nullptr, nullptr, B_SZ * N_SEQ, QKS, D_MODEL,
                  by * BM, bx * BN);
    } else {
        if (blockIdx.y * BM >= 3072 || blockIdx.x * BN >= HDK) return;
        gemm_body(posb, wrelt, relkb, nullptr, nullptr, 3072, HDK, NRPF,  // row 3071 -> 0
                  blockIdx.y * BM, blockIdx.x * BN);
    }
}

// -------- V transpose from fused qkv: qkv[b*N+n][1024 + h*192+c] -> vt[(b*8+h)*192+c][n]
__global__ __launch_bounds__(256) void transpose_v(const u16* __restrict__ qkv,
                                                   u16* __restrict__ vt) {
    __shared__ u16 tile[64][72];
    int nt = blockIdx.x, ct = blockIdx.y, bh = blockIdx.z;
    int b = bh >> 3, h = bh & 7;
    int tid = threadIdx.x;
    for (int t = tid; t < 512; t += 256) {
        int r = t >> 3, ch = t & 7;
        short8 v = *(const short8*)(qkv + ((size_t)(b * N_SEQ + nt * 64 + r)) * QKS
                                        + 1024 + h * DV + ct * 64 + ch * 8);
        #pragma unroll
        for (int e = 0; e < 8; ++e) tile[ch * 8 + e][r] = (u16)v[e];
    }
    __syncthreads();
    for (int t = tid; t < 512; t += 256) {
        int c = t >> 3, ch = t & 7;
        short8 v;
        #pragma unroll
        for (int e = 0; e < 8; ++e) v[e] = (short)tile[c][ch * 8 + e];
        *(short8*)(vt + ((size_t)((b * 8 + h) * DV + ct * 64 + c)) * N_SEQ
                      + nt * 64 + ch * 8) = v;
    }
}

// ---------------- MFMA flash attention: PV column-split + top-of-jt V prefetch -------
// r13 schedule (proven 99 us) with ONE change: the 6 PV V-fragment loads are issued
// at the TOP of jt (plain source motion, no sched_barrier pinning) so their L2
// latency hides under staging-issue + QK + softmax instead of stalling PV after the
// mid barrier. +24 VGPR held across the phase (~110 total, < 170 cap for 3 w/SIMD).
__global__ __launch_bounds__(256, 3) void attn_mfma(
    const u16* __restrict__ qb, const u16* __restrict__ kb,
    const u16* __restrict__ vtb, const u16* __restrict__ relkb,
    const float* __restrict__ cbias, const float* __restrict__ pbias,
    u16* __restrict__ att) {
    __shared__ u16 sK[2 * 64 * 64] __attribute__((aligned(16)));  // 16 KB K dbuf (Qc prologue)
    __shared__ u16 sP[64 * 64] __attribute__((aligned(16)));      //  8 KB P (Qp prologue)
    __shared__ u16 sRW[192 * 64] __attribute__((aligned(16)));    // 24 KB rel circular window
    __shared__ float sL[64];                                      // 256 B row denominators

    const int tid  = threadIdx.x;
    const int lane = tid & 63;
    const int w    = tid >> 6;
    const int h    = blockIdx.x & 7;
    const int q9   = blockIdx.x >> 3;        // 0..95
    const int b    = q9 / 24;
    const int i0   = (q9 % 24) * 64;
    const int rbase0 = (N_SEQ - 64) - i0;    // rel row of window-local 0

    const int c15 = lane & 15;
    const int g   = lane >> 4;
    const int g4  = g << 2;
    const int arow = w * 16 + c15;
    const int growb = w * 16 + g4;

    // ---- prologue: stage Q (+ biases): Qc -> sK buf0, Qp -> sP ----
    for (int t = tid; t < 512; t += 256) {
        const int row = t >> 3, ch = t & 7;
        short8 v = *(const short8*)(qb + ((size_t)(b * N_SEQ + i0 + row)) * QKS
                                       + h * DK + ch * 8);
        short8 c8, p8;
        #pragma unroll
        for (int e = 0; e < 8; ++e) {
            float f = bf2f((u16)v[e]);
            c8[e] = (short)f2bf(f + cbias[h * DK + ch * 8 + e]);
            p8[e] = (short)f2bf(f + pbias[h * DK + ch * 8 + e]);
        }
        const int dst = row * 64 + ((ch ^ (row & 7)) * 8);
        *(short8*)&sK[dst] = c8;
        *(short8*)&sP[dst] = p8;
    }
    __syncthreads();

    short8 aqc[2], aqp[2];
    #pragma unroll
    for (int s = 0; s < 2; ++s) {
        const int off = arow * 64 + (((s * 4 + g) ^ (arow & 7)) * 8);
        aqc[s] = *(const short8*)&sK[off];
        aqp[s] = *(const short8*)&sP[off];
    }
    __syncthreads();   // frag reads done before sK is restaged

    // ---- DMA staging helpers: pre-swizzled global source, linear LDS dest ----
    auto stage_k = [&](int j0s, int buf) {     // 64 rows -> sK[buf]
        #pragma unroll
        for (int i = 0; i < 2; ++i) {
            const int ci = i * 256 + tid, row = ci >> 3;
            const int sch = ((ci & 7) ^ (row & 7)) * 8;
            gload16(kb + ((size_t)(b * N_SEQ + j0s + row)) * QKS + h * DK + sch,
                    sK + buf * 4096 + ci * 8);
        }
    };
    auto stage_r = [&](int lr0) {              // 64 window rows [lr0, lr0+64)
        const int pw0 = lr0 % 192;             // multiple of 64
        #pragma unroll
        for (int i = 0; i < 2; ++i) {
            const int ci = i * 256 + tid, row = ci >> 3;
            const int sch = ((ci & 7) ^ (row & 7)) * 8;
            gload16(relkb + ((size_t)(rbase0 + lr0 + row)) * HDK + h * DK + sch,
                    sRW + pw0 * 64 + ci * 8);
        }
    };

    // ---- DMA prologue: K buf0 (jt=0) + rel window rows [0,128) ----
    stage_k(0, 0);
    stage_r(0);
    stage_r(64);
    asm volatile("s_waitcnt vmcnt(0) lgkmcnt(0)" ::: "memory");
    __builtin_amdgcn_sched_barrier(0);
    __builtin_amdgcn_s_barrier();

    f32x4 O[12];   // O[rf*3 + cf3]: rows rf*16+4g+r, cols 48w + cf3*16 + c15
    #pragma unroll
    for (int i = 0; i < 12; ++i) O[i] = (f32x4){0.f, 0.f, 0.f, 0.f};
    float L[4] = {0.f, 0.f, 0.f, 0.f};

    const u16* vwave = vtb + ((size_t)((b * 8 + h) * DV + w * 48 + c15)) * N_SEQ + 8 * g;

    for (int jt = 0; jt < 24; ++jt) {
        const int j0 = jt * 64;
        // ---- V prefetch for THIS jt: issued first, consumed in PV below.
        // Latency hides under staging-issue + QK + softmax (~2000 cyc).
        short8 vf0[3], vf1[3];
        #pragma unroll
        for (int cf3 = 0; cf3 < 3; ++cf3) {
            vf0[cf3] = *(const short8*)(vwave + j0 + (size_t)cf3 * 16 * N_SEQ);
            vf1[cf3] = *(const short8*)(vwave + j0 + 32 + (size_t)cf3 * 16 * N_SEQ);
        }
        // ---- issue DMA staging for jt+1 (lands by end-of-jt barrier) ----
        if (jt < 23) {
            stage_k(j0 + 64, (jt + 1) & 1);
            stage_r(j0 + 128);
        }
        // ---- QK^T strip (4 frags) + rel window strip (5 frags, wave-specific) ----
        f32x4 S[4], G5[5];
        #pragma unroll
        for (int f = 0; f < 4; ++f) S[f] = (f32x4){0.f, 0.f, 0.f, 0.f};
        #pragma unroll
        for (int t = 0; t < 5; ++t) G5[t] = (f32x4){0.f, 0.f, 0.f, 0.f};
        const int kbase = (jt & 1) * 4096;
        const int ph = (jt % 3) * 64;            // circular window phase
        #pragma unroll
        for (int s = 0; s < 2; ++s) {
            short8 kf[4], rf[5];
            #pragma unroll
            for (int f = 0; f < 4; ++f) {
                const int br = f * 16 + c15;
                kf[f] = *(const short8*)&sK[kbase + br * 64 + (((s * 4 + g) ^ (br & 7)) * 8)];
            }
            #pragma unroll
            for (int t = 0; t < 5; ++t) {
                int lrb = ph + (3 - w + t) * 16;
                if (lrb >= 192) lrb -= 192;
                const int pr = lrb + c15;
                rf[t] = *(const short8*)&sRW[pr * 64 + (((s * 4 + g) ^ (pr & 7)) * 8)];
            }
            #pragma unroll
            for (int f = 0; f < 4; ++f) S[f] = MFMA_B16(aqc[s], kf[f], S[f]);
            #pragma unroll
            for (int t = 0; t < 5; ++t) G5[t] = MFMA_B16(aqp[s], rf[t], G5[t]);
        }
        // ---- in-register relative shift: S[jf][r] += G[ii][63+jj-ii] ----
        #pragma unroll
        for (int r = 0; r < 4; ++r) {
            const int src = (lane & 48) | ((c15 + 15 - g4 - r) & 15);
            const float rot0 = __shfl(G5[0][r], src, 64);
            const float rot1 = __shfl(G5[1][r], src, 64);
            const float rot2 = __shfl(G5[2][r], src, 64);
            const float rot3 = __shfl(G5[3][r], src, 64);
            const float rot4 = __shfl(G5[4][r], src, 64);
            const bool wrap = (c15 - g4) > r;
            S[0][r] += wrap ? rot1 : rot0;
            S[1][r] += wrap ? rot2 : rot1;
            S[2][r] += wrap ? rot3 : rot2;
            S[3][r] += wrap ? rot4 : rot3;
        }
        // ---- fixed-base softmax: p = exp(S-12); L accumulated in-lane only ----
        #pragma unroll
        for (int r = 0; r < 4; ++r) {
            #pragma unroll
            for (int f = 0; f < 4; ++f) {
                const float pe = __expf(S[f][r] - SM_BASE);
                S[f][r] = pe;
                L[r] += pe;
            }
        }
        // ---- P -> bf16 into sP (own 16 rows) ----
        #pragma unroll
        for (int f = 0; f < 4; ++f) {
            const int jj = f * 16 + c15;
            #pragma unroll
            for (int r = 0; r < 4; ++r) {
                const int ii = growb + r;
                sP[ii * 64 + (((jj >> 3) ^ (ii & 7)) * 8) + (jj & 7)] = f2bf(S[f][r]);
            }
        }
        // ---- mid barrier: all waves' P visible (LDS-only wait, no vmcnt drain) ----
        asm volatile("s_waitcnt lgkmcnt(0)" ::: "memory");
        __builtin_amdgcn_sched_barrier(0);
        __builtin_amdgcn_s_barrier();
        // ---- PV col-split: wave w owns cols [48w, 48w+48); V frags already in regs ----
        #pragma unroll
        for (int rfi = 0; rfi < 4; ++rfi) {
            const int prow = rfi * 16 + c15;
            short8 a0 = *(const short8*)&sP[prow * 64 + ((g ^ (prow & 7)) * 8)];
            #pragma unroll
            for (int cf3 = 0; cf3 < 3; ++cf3)
                O[rfi * 3 + cf3] = MFMA_B16(a0, vf0[cf3], O[rfi * 3 + cf3]);
        }
        #pragma unroll
        for (int rfi = 0; rfi < 4; ++rfi) {
            const int prow = rfi * 16 + c15;
            short8 a1 = *(const short8*)&sP[prow * 64 + (((4 + g) ^ (prow & 7)) * 8)];
            #pragma unroll
            for (int cf3 = 0; cf3 < 3; ++cf3)
                O[rfi * 3 + cf3] = MFMA_B16(a1, vf1[cf3], O[rfi * 3 + cf3]);
        }
        // ---- single end-of-jt barrier: staging DMA landed, LDS reads done ----
        asm volatile("s_waitcnt vmcnt(0) lgkmcnt(0)" ::: "memory");
        __builtin_amdgcn_sched_barrier(0);
        __builtin_amdgcn_s_barrier();
    }
    // ---- epilogue: reduce L over 16-lane groups, exchange via sL, store ----
    #pragma unroll
    for (int r = 0; r < 4; ++r) {
        float l = L[r];
        l += __shfl_xor(l, 1, 64);
        l += __shfl_xor(l, 2, 64);
        l += __shfl_xor(l, 4, 64);
        l += __shfl_xor(l, 8, 64);
        L[r] = l;
    }
    if (c15 == 0) {
        #pragma unroll
        for (int r = 0; r < 4; ++r) sL[growb + r] = L[r];
    }
    __syncthreads();
    #pragma unroll
    for (int rfi = 0; rfi < 4; ++rfi) {
        #pragma unroll
        for (int r = 0; r < 4; ++r) {
            const int row = rfi * 16 + g4 + r;
            const float inv = 1.0f / sL[row];
            #pragma unroll
            for (int cf3 = 0; cf3 < 3; ++cf3) {
                att[((size_t)(b * N_SEQ + i0 + row)) * HDV + h * DV
                    + w * 48 + cf3 * 16 + c15] = f2bf(O[rfi * 3 + cf3][r] * inv);
            }
        }
    }
}

extern "C" void kernel_launch(void* const* d_in, const int* in_sizes, int n_in,
                              void* d_out, int out_size, void* d_ws, size_t ws_size,
                              hipStream_t stream) {
    const float* x    = (const float*)d_in[0];
    const float* Wq   = (const float*)d_in[1];
    const float* Wk   = (const float*)d_in[2];
    const float* Wv   = (const float*)d_in[3];
    const float* Wrel = (const float*)d_in[4];
    const float* cb   = (const float*)d_in[5];
    const float* pb   = (const float*)d_in[6];
    const float* Wout = (const float*)d_in[7];
    const float* bout = (const float*)d_in[8];
    float* out = (float*)d_out;

    const int M = B_SZ * N_SEQ;                 // 6144
    u16* ws16  = (u16*)d_ws;
    u16* xb    = ws16;                          // 6144x1536 (reused as att later)
    u16* qkvb  = xb    + (size_t)M * HDV;       // 6144x2560 (q | k | v)
    u16* vtb   = qkvb  + (size_t)M * QKS;       // 32x192x1536
    u16* posb  = vtb   + (size_t)M * HDV;       // 3072x192
    u16* relkb = posb  + (size_t)3072 * NRPF;   // 3072x512 (row 3071 = 0)
    u16* wqkvt = relkb + (size_t)3072 * HDK;    // 2560x1536
    u16* woutt = wqkvt + (size_t)QKS * D_MODEL; // 1536x1536
    u16* wrelt = woutt + (size_t)D_MODEL * HDV; // 512x192
    u16* attb  = xb;                            // alias: xb dead after QKV projection

    dim3 blk(256);
    prep_kernel<<<dim3(64, 48, 7), blk, 0, stream>>>(
        x, Wq, Wk, Wv, Wout, Wrel, posb, xb, wqkvt, woutt, wrelt);
    gemm_qkv_rel<<<dim3(QKS / BN, M / BM, 2), blk, 0, stream>>>(
        xb, wqkvt, qkvb, posb, wrelt, relkb);
    transpose_v<<<dim3(N_SEQ / 64, DV / 64, B_SZ * H_N), blk, 0, stream>>>(qkvb, vtb);
    attn_mfma<<<768, blk, 0, stream>>>(
        qkvb, qkvb + 512, vtb, relkb, cb, pb, attb);
    gemm_bf16<<<dim3(D_MODEL / BN, M / BM), blk, 0, stream>>>(
        attb, woutt, nullptr, out, bout, M, D_MODEL, HDV);
}

// Round 20
// 258.755 us; speedup vs baseline: 1.1309x; 1.1309x over previous
//
#include <hip/hip_runtime.h>
#include <cmath>

#define B_SZ    4
#define N_SEQ   1536
#define D_MODEL 1536
#define H_N     8
#define DK      64
#define DV      192
#define HDK     512
#define HDV     1536
#define NRPF    192
#define NB      32
#define NREL    3071
#define QKS     2560   // row stride of fused q|k|v buffer
#define SM_BASE 12.0f  // fixed softmax base: p = exp(S - SM_BASE); |S| <= ~30 (verified r8)

typedef unsigned short u16;
typedef __attribute__((ext_vector_type(8))) short short8;
typedef __attribute__((ext_vector_type(4))) float f32x4;

#define MFMA_B16(a, b, c) __builtin_amdgcn_mfma_f32_16x16x32_bf16(a, b, c, 0, 0, 0)

__device__ __forceinline__ float bf2f(u16 u) {
    union { unsigned u; float f; } x; x.u = ((unsigned)u) << 16; return x.f;
}
__device__ __forceinline__ u16 f2bf(float f) {
    union { float f; unsigned u; } x; x.f = f;
    unsigned r = x.u + 0x7FFFu + ((x.u >> 16) & 1u);
    return (u16)(r >> 16);
}
__device__ __forceinline__ void gload16(const u16* g, u16* l) {
    __builtin_amdgcn_global_load_lds(
        (const __attribute__((address_space(1))) unsigned int*)(const void*)g,
        (__attribute__((address_space(3))) unsigned int*)(void*)l, 16, 0, 0);
}

// ---------------- fused prep: weight transposes (z=0..4), pos embed (z=5), cvt (z=6) --
// grid dim3(64, 48, 7), 256 threads.
__global__ __launch_bounds__(256) void prep_kernel(
    const float* __restrict__ x,
    const float* __restrict__ Wq, const float* __restrict__ Wk,
    const float* __restrict__ Wv, const float* __restrict__ Wout,
    const float* __restrict__ Wrel,
    u16* __restrict__ posb, u16* __restrict__ xb,
    u16* __restrict__ wqkvt, u16* __restrict__ woutt, u16* __restrict__ wrelt) {
    const int z = blockIdx.z;
    const int tid = threadIdx.x;
    if (z < 5) {
        // ---- weight transpose: W (KxN f32) -> Wt (NxK bf16), scaled ----
        const float* W; u16* Wt; int K, N; float scale = 1.0f;
        if (z == 0)      { W = Wq;   Wt = wqkvt;                        K = 1536; N = 512;  scale = 0.125f; }
        else if (z == 1) { W = Wk;   Wt = wqkvt + (size_t)512 * 1536;   K = 1536; N = 512;  }
        else if (z == 2) { W = Wv;   Wt = wqkvt + (size_t)1024 * 1536;  K = 1536; N = 1536; }
        else if (z == 3) { W = Wout; Wt = woutt;                        K = 1536; N = 1536; }
        else             { W = Wrel; Wt = wrelt;                        K = 192;  N = 512;  }
        __shared__ float tile[32][33];
        int n0 = blockIdx.x * 32, k0 = blockIdx.y * 32;
        if (n0 >= N || k0 >= K) return;
        int tx = tid & 31, ty = tid >> 5;
        for (int r = ty; r < 32; r += 8) tile[r][tx] = W[(size_t)(k0 + r) * N + n0 + tx];
        __syncthreads();
        for (int r = ty; r < 32; r += 8)
            Wt[(size_t)(n0 + r) * K + k0 + tx] = f2bf(tile[tx][r] * scale);
    } else if (z == 5) {
        // ---- positional embedding -> bf16 (3072 x 192, row 3071 = 0) ----
        const int r = blockIdx.y * 64 + blockIdx.x;   // 0..3071
        const int j = tid;                            // only 0..95 active
        if (r >= NREL) {
            if (j < 96) {
                posb[(size_t)r * NRPF + j] = 0;
                posb[(size_t)r * NRPF + 96 + j] = 0;
            }
            return;
        }
        __shared__ float gprobs[NB];
        float dist = (float)(r - (N_SEQ - 1));
        float absd = fabsf(dist);
        int cls = j >> 5, jj = j & 31;
        float val = 0.0f;
        if (j < 96) {
            if (cls == 0) {
                const float max_range = 10.584962500721156f; // log2(1536)
                float hl = exp2f(3.0f + (float)jj * (max_range - 3.0f) / 31.0f);
                val = expf(-0.6931471805599453f / hl * absd);
            } else if (cls == 1) {
                float cw = exp2f((float)(jj + 1)) - 1.0f;
                val = (cw > absd) ? 1.0f : 0.0f;
            } else {
                float mean = 48.0f + (float)jj * (1536.0f - 48.0f) / 31.0f;
                float conc = (mean / 24.0f) * (mean / 24.0f);
                float rate = mean / 576.0f;
                float lu = (conc - 1.0f) * logf(absd) - rate * absd;
                float ln = lgammaf(conc) - conc * logf(rate);
                float prob = expf(lu - ln) + 1e-8f;
                gprobs[jj] = prob;
                val = prob;
            }
        }
        __syncthreads();
        if (j < 96) {
            if (cls == 2) {
                float mx = gprobs[0];
                #pragma unroll
                for (int t = 1; t < NB; ++t) mx = fmaxf(mx, gprobs[t]);
                val = val / mx;
            }
            float sgn = (dist > 0.f) ? 1.f : ((dist < 0.f) ? -1.f : 0.f);
            posb[(size_t)r * NRPF + j]      = f2bf(val);
            posb[(size_t)r * NRPF + 96 + j] = f2bf(sgn * val);
        }
    } else {
        // ---- x f32 -> bf16, grid-stride (n8 = 6144*1536/8) ----
        const int n8 = (B_SZ * N_SEQ) * D_MODEL / 8;
        const float4* p = (const float4*)x;
        for (int i = (blockIdx.y * 64 + blockIdx.x) * 256 + tid; i < n8; i += 64 * 48 * 256) {
            float4 a = p[i * 2], bq = p[i * 2 + 1];
            short8 o;
            o[0] = (short)f2bf(a.x);  o[1] = (short)f2bf(a.y);
            o[2] = (short)f2bf(a.z);  o[3] = (short)f2bf(a.w);
            o[4] = (short)f2bf(bq.x); o[5] = (short)f2bf(bq.y);
            o[6] = (short)f2bf(bq.z); o[7] = (short)f2bf(bq.w);
            *(short8*)(xb + (size_t)i * 8) = o;
        }
    }
}

// ---------------- bf16 MFMA GEMM body: C = A @ Bt^T (+bias) -----------------
#define BM 128
#define BN 128
#define BK 64
__device__ __forceinline__ void gemm_body(
    const u16* __restrict__ A, const u16* __restrict__ Bt,
    u16* __restrict__ Cb, float* __restrict__ Cf,
    const float* __restrict__ bias, int Mstore, int N, int K,
    int row0, int col0) {
    __shared__ u16 sA[BM * BK] __attribute__((aligned(16)));
    __shared__ u16 sB[BN * BK] __attribute__((aligned(16)));
    const int tid  = threadIdx.x;
    const int lane = tid & 63;
    const int w    = tid >> 6;
    const int wm   = w >> 1, wn = w & 1;

    f32x4 acc[4][4];
    #pragma unroll
    for (int i = 0; i < 4; ++i)
        #pragma unroll
        for (int j = 0; j < 4; ++j) acc[i][j] = (f32x4){0.f, 0.f, 0.f, 0.f};

    int srow[4], soff[4];
    #pragma unroll
    for (int i = 0; i < 4; ++i) {
        const int ci = i * 256 + tid;
        const int r  = ci >> 3;
        const int lc = (ci & 7) ^ (r & 7);
        srow[i] = r;
        soff[i] = lc * 8;
    }

    for (int kt = 0; kt < K; kt += BK) {
        #pragma unroll
        for (int i = 0; i < 4; ++i) {
            gload16(A + (size_t)(row0 + srow[i]) * K + kt + soff[i],
                    sA + (i * 256 + w * 64) * 8);
            gload16(Bt + (size_t)(col0 + srow[i]) * K + kt + soff[i],
                    sB + (i * 256 + w * 64) * 8);
        }
        __syncthreads();
        short8 af[2][4], bg[2][4];
        #pragma unroll
        for (int s = 0; s < 2; ++s) {
            #pragma unroll
            for (int mi = 0; mi < 4; ++mi) {
                const int rr = wm * 64 + mi * 16 + (lane & 15);
                af[s][mi] = *(const short8*)&sA[rr * 64 + (((s * 4 + (lane >> 4)) ^ (rr & 7)) * 8)];
            }
            #pragma unroll
            for (int ni = 0; ni < 4; ++ni) {
                const int rr = wn * 64 + ni * 16 + (lane & 15);
                bg[s][ni] = *(const short8*)&sB[rr * 64 + (((s * 4 + (lane >> 4)) ^ (rr & 7)) * 8)];
            }
        }
        #pragma unroll
        for (int s = 0; s < 2; ++s)
            #pragma unroll
            for (int mi = 0; mi < 4; ++mi)
                #pragma unroll
                for (int ni = 0; ni < 4; ++ni)
                    acc[mi][ni] = MFMA_B16(af[s][mi], bg[s][ni], acc[mi][ni]);
        __syncthreads();
    }
    const int rb = (lane >> 4) * 4;
    const int cl = lane & 15;
    #pragma unroll
    for (int mi = 0; mi < 4; ++mi) {
        #pragma unroll
        for (int r = 0; r < 4; ++r) {
            const int gr = row0 + wm * 64 + mi * 16 + rb + r;
            if (gr >= Mstore) continue;
            #pragma unroll
            for (int ni = 0; ni < 4; ++ni) {
                const int gc = col0 + wn * 64 + ni * 16 + cl;
                float v = acc[mi][ni][r];
                if (bias) v += bias[gc];
                if (Cb) Cb[(size_t)gr * N + gc] = f2bf(v);
                else    Cf[(size_t)gr * N + gc] = v;
            }
        }
    }
}

// T1 XCD swizzle: pin each A-row-panel's full column sweep to one XCD.
// Requires gy % 8 == 0 (bijective; ERRATA #11). flat follows dispatch order.
__device__ __forceinline__ void xcd_swz(int gx, int gy, int& bx, int& by) {
    const int flat = blockIdx.x + gx * blockIdx.y;
    const int ypg  = gy >> 3;             // y-panels per XCD
    const int xcd  = flat & 7;
    const int q    = flat >> 3;
    by = xcd * ypg + (q % ypg);
    bx = q / ypg;
}

__global__ __launch_bounds__(256) void gemm_bf16(
    const u16* __restrict__ A, const u16* __restrict__ Bt,
    u16* __restrict__ Cb, float* __restrict__ Cf,
    const float* __restrict__ bias, int Mstore, int N, int K) {
    int bx, by;
    xcd_swz(gridDim.x, gridDim.y, bx, by);
    gemm_body(A, Bt, Cb, Cf, bias, Mstore, N, K, by * BM, bx * BN);
}

// ---- fused QKV + rel GEMMs: z=0 QKV (6144x2560x1536, XCD-swizzled),
// ---- z=1 rel (3072x512x192, plain mapping + guard) ----
__global__ __launch_bounds__(256) void gemm_qkv_rel(
    const u16* __restrict__ xb, const u16* __restrict__ wqkvt, u16* __restrict__ qkvb,
    const u16* __restrict__ posb, const u16* __restrict__ wrelt, u16* __restrict__ relkb) {
    if (blockIdx.z == 0) {
        int bx, by;
        xcd_swz(QKS / BN, (B_SZ * N_SEQ) / BM, bx, by);   // 20 x 48
        gemm_body(xb, wqkvt, qkvb, nullptr, nullptr, B_SZ * N_SEQ, QKS, D_MODEL,
                  by * BM, bx * BN);
    } else {
        if (blockIdx.y * BM >= 3072 || blockIdx.x * BN >= HDK) return;
        gemm_body(posb, wrelt, relkb, nullptr, nullptr, 3072, HDK, NRPF,  // row 3071 -> 0
                  blockIdx.y * BM, blockIdx.x * BN);
    }
}

// -------- V transpose from fused qkv: qkv[b*N+n][1024 + h*192+c] -> vt[(b*8+h)*192+c][n]
__global__ __launch_bounds__(256) void transpose_v(const u16* __restrict__ qkv,
                                                   u16* __restrict__ vt) {
    __shared__ u16 tile[64][72];
    int nt = blockIdx.x, ct = blockIdx.y, bh = blockIdx.z;
    int b = bh >> 3, h = bh & 7;
    int tid = threadIdx.x;
    for (int t = tid; t < 512; t += 256) {
        int r = t >> 3, ch = t & 7;
        short8 v = *(const short8*)(qkv + ((size_t)(b * N_SEQ + nt * 64 + r)) * QKS
                                        + 1024 + h * DV + ct * 64 + ch * 8);
        #pragma unroll
        for (int e = 0; e < 8; ++e) tile[ch * 8 + e][r] = (u16)v[e];
    }
    __syncthreads();
    for (int t = tid; t < 512; t += 256) {
        int c = t >> 3, ch = t & 7;
        short8 v;
        #pragma unroll
        for (int e = 0; e < 8; ++e) v[e] = (short)tile[c][ch * 8 + e];
        *(short8*)(vt + ((size_t)((b * 8 + h) * DV + ct * 64 + c)) * N_SEQ
                      + nt * 64 + ch * 8) = v;
    }
}

// ---------------- MFMA flash attention: PV column-split across waves ----------------
// (round-13 proven kernel: 99 us, MfmaUtil 21%, FETCH 20 MB — FINAL)
__global__ __launch_bounds__(256, 3) void attn_mfma(
    const u16* __restrict__ qb, const u16* __restrict__ kb,
    const u16* __restrict__ vtb, const u16* __restrict__ relkb,
    const float* __restrict__ cbias, const float* __restrict__ pbias,
    u16* __restrict__ att) {
    __shared__ u16 sK[2 * 64 * 64] __attribute__((aligned(16)));  // 16 KB K dbuf (Qc prologue)
    __shared__ u16 sP[64 * 64] __attribute__((aligned(16)));      //  8 KB P (Qp prologue)
    __shared__ u16 sRW[192 * 64] __attribute__((aligned(16)));    // 24 KB rel circular window
    __shared__ float sL[64];                                      // 256 B row denominators

    const int tid  = threadIdx.x;
    const int lane = tid & 63;
    const int w    = tid >> 6;
    const int h    = blockIdx.x & 7;
    const int q9   = blockIdx.x >> 3;        // 0..95
    const int b    = q9 / 24;
    const int i0   = (q9 % 24) * 64;
    const int rbase0 = (N_SEQ - 64) - i0;    // rel row of window-local 0

    const int c15 = lane & 15;
    const int g   = lane >> 4;
    const int g4  = g << 2;
    const int arow = w * 16 + c15;
    const int growb = w * 16 + g4;

    // ---- prologue: stage Q (+ biases): Qc -> sK buf0, Qp -> sP ----
    for (int t = tid; t < 512; t += 256) {
        const int row = t >> 3, ch = t & 7;
        short8 v = *(const short8*)(qb + ((size_t)(b * N_SEQ + i0 + row)) * QKS
                                       + h * DK + ch * 8);
        short8 c8, p8;
        #pragma unroll
        for (int e = 0; e < 8; ++e) {
            float f = bf2f((u16)v[e]);
            c8[e] = (short)f2bf(f + cbias[h * DK + ch * 8 + e]);
            p8[e] = (short)f2bf(f + pbias[h * DK + ch * 8 + e]);
        }
        const int dst = row * 64 + ((ch ^ (row & 7)) * 8);
        *(short8*)&sK[dst] = c8;
        *(short8*)&sP[dst] = p8;
    }
    __syncthreads();

    short8 aqc[2], aqp[2];
    #pragma unroll
    for (int s = 0; s < 2; ++s) {
        const int off = arow * 64 + (((s * 4 + g) ^ (arow & 7)) * 8);
        aqc[s] = *(const short8*)&sK[off];
        aqp[s] = *(const short8*)&sP[off];
    }
    __syncthreads();   // frag reads done before sK is restaged

    // ---- DMA staging helpers: pre-swizzled global source, linear LDS dest ----
    auto stage_k = [&](int j0s, int buf) {     // 64 rows -> sK[buf]
        #pragma unroll
        for (int i = 0; i < 2; ++i) {
            const int ci = i * 256 + tid, row = ci >> 3;
            const int sch = ((ci & 7) ^ (row & 7)) * 8;
            gload16(kb + ((size_t)(b * N_SEQ + j0s + row)) * QKS + h * DK + sch,
                    sK + buf * 4096 + ci * 8);
        }
    };
    auto stage_r = [&](int lr0) {              // 64 window rows [lr0, lr0+64)
        const int pw0 = lr0 % 192;             // multiple of 64
        #pragma unroll
        for (int i = 0; i < 2; ++i) {
            const int ci = i * 256 + tid, row = ci >> 3;
            const int sch = ((ci & 7) ^ (row & 7)) * 8;
            gload16(relkb + ((size_t)(rbase0 + lr0 + row)) * HDK + h * DK + sch,
                    sRW + pw0 * 64 + ci * 8);
        }
    };

    // ---- DMA prologue: K buf0 (jt=0) + rel window rows [0,128) ----
    stage_k(0, 0);
    stage_r(0);
    stage_r(64);
    asm volatile("s_waitcnt vmcnt(0) lgkmcnt(0)" ::: "memory");
    __builtin_amdgcn_sched_barrier(0);
    __builtin_amdgcn_s_barrier();

    f32x4 O[12];   // O[rf*3 + cf3]: rows rf*16+4g+r, cols 48w + cf3*16 + c15
    #pragma unroll
    for (int i = 0; i < 12; ++i) O[i] = (f32x4){0.f, 0.f, 0.f, 0.f};
    float L[4] = {0.f, 0.f, 0.f, 0.f};

    for (int jt = 0; jt < 24; ++jt) {
        const int j0 = jt * 64;
        // ---- issue DMA staging for jt+1 (lands by end-of-jt barrier) ----
        if (jt < 23) {
            stage_k(j0 + 64, (jt + 1) & 1);
            stage_r(j0 + 128);
        }
        // ---- QK^T strip (4 frags) + rel window strip (5 frags, wave-specific) ----
        f32x4 S[4], G5[5];
        #pragma unroll
        for (int f = 0; f < 4; ++f) S[f] = (f32x4){0.f, 0.f, 0.f, 0.f};
        #pragma unroll
        for (int t = 0; t < 5; ++t) G5[t] = (f32x4){0.f, 0.f, 0.f, 0.f};
        const int kbase = (jt & 1) * 4096;
        const int ph = (jt % 3) * 64;            // circular window phase
        #pragma unroll
        for (int s = 0; s < 2; ++s) {
            short8 kf[4], rf[5];
            #pragma unroll
            for (int f = 0; f < 4; ++f) {
                const int br = f * 16 + c15;
                kf[f] = *(const short8*)&sK[kbase + br * 64 + (((s * 4 + g) ^ (br & 7)) * 8)];
            }
            #pragma unroll
            for (int t = 0; t < 5; ++t) {
                int lrb = ph + (3 - w + t) * 16;
                if (lrb >= 192) lrb -= 192;
                const int pr = lrb + c15;
                rf[t] = *(const short8*)&sRW[pr * 64 + (((s * 4 + g) ^ (pr & 7)) * 8)];
            }
            #pragma unroll
            for (int f = 0; f < 4; ++f) S[f] = MFMA_B16(aqc[s], kf[f], S[f]);
            #pragma unroll
            for (int t = 0; t < 5; ++t) G5[t] = MFMA_B16(aqp[s], rf[t], G5[t]);
        }
        // ---- in-register relative shift: S[jf][r] += G[ii][63+jj-ii] ----
        #pragma unroll
        for (int r = 0; r < 4; ++r) {
            const int src = (lane & 48) | ((c15 + 15 - g4 - r) & 15);
            const float rot0 = __shfl(G5[0][r], src, 64);
            const float rot1 = __shfl(G5[1][r], src, 64);
            const float rot2 = __shfl(G5[2][r], src, 64);
            const float rot3 = __shfl(G5[3][r], src, 64);
            const float rot4 = __shfl(G5[4][r], src, 64);
            const bool wrap = (c15 - g4) > r;
            S[0][r] += wrap ? rot1 : rot0;
            S[1][r] += wrap ? rot2 : rot1;
            S[2][r] += wrap ? rot3 : rot2;
            S[3][r] += wrap ? rot4 : rot3;
        }
        // ---- fixed-base softmax: p = exp(S-12); L accumulated in-lane only ----
        #pragma unroll
        for (int r = 0; r < 4; ++r) {
            #pragma unroll
            for (int f = 0; f < 4; ++f) {
                const float pe = __expf(S[f][r] - SM_BASE);
                S[f][r] = pe;
                L[r] += pe;
            }
        }
        // ---- P -> bf16 into sP (own 16 rows) ----
        #pragma unroll
        for (int f = 0; f < 4; ++f) {
            const int jj = f * 16 + c15;
            #pragma unroll
            for (int r = 0; r < 4; ++r) {
                const int ii = growb + r;
                sP[ii * 64 + (((jj >> 3) ^ (ii & 7)) * 8) + (jj & 7)] = f2bf(S[f][r]);
            }
        }
        // ---- mid barrier: all waves' P visible (LDS-only wait, no vmcnt drain) ----
        asm volatile("s_waitcnt lgkmcnt(0)" ::: "memory");
        __builtin_amdgcn_sched_barrier(0);
        __builtin_amdgcn_s_barrier();
        // ---- PV col-split: wave w owns cols [48w, 48w+48); V frags reused x4 ----
        #pragma unroll
        for (int s = 0; s < 2; ++s) {
            const u16* vp = vtb + ((size_t)((b * 8 + h) * DV + w * 48 + c15)) * N_SEQ
                                + j0 + s * 32 + 8 * g;
            short8 vf[3];
            #pragma unroll
            for (int cf3 = 0; cf3 < 3; ++cf3)
                vf[cf3] = *(const short8*)(vp + (size_t)cf3 * 16 * N_SEQ);
            #pragma unroll
            for (int rfi = 0; rfi < 4; ++rfi) {
                const int prow = rfi * 16 + c15;
                short8 a = *(const short8*)&sP[prow * 64 + (((s * 4 + g) ^ (prow & 7)) * 8)];
                #pragma unroll
                for (int cf3 = 0; cf3 < 3; ++cf3)
                    O[rfi * 3 + cf3] = MFMA_B16(a, vf[cf3], O[rfi * 3 + cf3]);
            }
        }
        // ---- single end-of-jt barrier: staging DMA landed, LDS reads done ----
        asm volatile("s_waitcnt vmcnt(0) lgkmcnt(0)" ::: "memory");
        __builtin_amdgcn_sched_barrier(0);
        __builtin_amdgcn_s_barrier();
    }
    // ---- epilogue: reduce L over 16-lane groups, exchange via sL, store ----
    #pragma unroll
    for (int r = 0; r < 4; ++r) {
        float l = L[r];
        l += __shfl_xor(l, 1, 64);
        l += __shfl_xor(l, 2, 64);
        l += __shfl_xor(l, 4, 64);
        l += __shfl_xor(l, 8, 64);
        L[r] = l;
    }
    if (c15 == 0) {
        #pragma unroll
        for (int r = 0; r < 4; ++r) sL[growb + r] = L[r];
    }
    __syncthreads();
    #pragma unroll
    for (int rfi = 0; rfi < 4; ++rfi) {
        #pragma unroll
        for (int r = 0; r < 4; ++r) {
            const int row = rfi * 16 + g4 + r;
            const float inv = 1.0f / sL[row];
            #pragma unroll
            for (int cf3 = 0; cf3 < 3; ++cf3) {
                att[((size_t)(b * N_SEQ + i0 + row)) * HDV + h * DV
                    + w * 48 + cf3 * 16 + c15] = f2bf(O[rfi * 3 + cf3][r] * inv);
            }
        }
    }
}

extern "C" void kernel_launch(void* const* d_in, const int* in_sizes, int n_in,
                              void* d_out, int out_size, void* d_ws, size_t ws_size,
                              hipStream_t stream) {
    const float* x    = (const float*)d_in[0];
    const float* Wq   = (const float*)d_in[1];
    const float* Wk   = (const float*)d_in[2];
    const float* Wv   = (const float*)d_in[3];
    const float* Wrel = (const float*)d_in[4];
    const float* cb   = (const float*)d_in[5];
    const float* pb   = (const float*)d_in[6];
    const float* Wout = (const float*)d_in[7];
    const float* bout = (const float*)d_in[8];
    float* out = (float*)d_out;

    const int M = B_SZ * N_SEQ;                 // 6144
    u16* ws16  = (u16*)d_ws;
    u16* xb    = ws16;                          // 6144x1536 (reused as att later)
    u16* qkvb  = xb    + (size_t)M * HDV;       // 6144x2560 (q | k | v)
    u16* vtb   = qkvb  + (size_t)M * QKS;       // 32x192x1536
    u16* posb  = vtb   + (size_t)M * HDV;       // 3072x192
    u16* relkb = posb  + (size_t)3072 * NRPF;   // 3072x512 (row 3071 = 0)
    u16* wqkvt = relkb + (size_t)3072 * HDK;    // 2560x1536
    u16* woutt = wqkvt + (size_t)QKS * D_MODEL; // 1536x1536
    u16* wrelt = woutt + (size_t)D_MODEL * HDV; // 512x192
    u16* attb  = xb;                            // alias: xb dead after QKV projection

    dim3 blk(256);
    prep_kernel<<<dim3(64, 48, 7), blk, 0, stream>>>(
        x, Wq, Wk, Wv, Wout, Wrel, posb, xb, wqkvt, woutt, wrelt);
    gemm_qkv_rel<<<dim3(QKS / BN, M / BM, 2), blk, 0, stream>>>(
        xb, wqkvt, qkvb, posb, wrelt, relkb);
    transpose_v<<<dim3(N_SEQ / 64, DV / 64, B_SZ * H_N), blk, 0, stream>>>(qkvb, vtb);
    attn_mfma<<<768, blk, 0, stream>>>(
        qkvb, qkvb + 512, vtb, relkb, cb, pb, attb);
    gemm_bf16<<<dim3(D_MODEL / BN, M / BM), blk, 0, stream>>>(
        attb, woutt, nullptr, out, bout, M, D_MODEL, HDV);
}